// Round 1
// 361.865 us; speedup vs baseline: 1.0756x; 1.0756x over previous
//
#include <hip/hip_runtime.h>

// Problem constants
#define B_ 32
#define C_ 64
#define O_ 64
#define H_ 128
#define W_ 128

typedef __attribute__((ext_vector_type(8))) short short8;   // 8 x bf16 (4 VGPRs)
typedef __attribute__((ext_vector_type(4))) short short4v;  // 4 x bf16 (2 VGPRs)
typedef __attribute__((ext_vector_type(4))) float f32x4;    // 4 x fp32 acc

typedef __attribute__((address_space(1))) const void gv_t;  // global
typedef __attribute__((address_space(3))) void lv_t;        // LDS

static __device__ __forceinline__ unsigned short f2bf(float f) {
    unsigned u = __builtin_bit_cast(unsigned, f);
    unsigned r = (u + 0x7FFFu + ((u >> 16) & 1u)) >> 16;    // RNE
    return (unsigned short)r;
}

static __device__ __forceinline__ unsigned pk_bf16(float lo, float hi) {
    unsigned r;
    asm("v_cvt_pk_bf16_f32 %0, %1, %2" : "=v"(r) : "v"(lo), "v"(hi));  // RNE, matches f2bf
    return r;
}

// ---------------- ws layout (float offsets) ----------------
#define WS_S      0         // [B*C*9]              18432
#define WS_COND2  18432     // [B*16]               512
#define WS_DW     18944     // [B*C*9]              18432
#define WS_DBIAS  37376     // [B*O]                2048
#define WS_PWBF   39424     // [B*O*C] bf16         65536 float slots
#define WS_PSUM   104960    // [2048][64]           131072
#define WS_PSQ    236032    // [2048][64]           131072
#define WS_SCALE  367104    // [O]
#define WS_SHIFT  367168    // [O]

// K1: per-(b,c) strided sums (unchanged)
__global__ void __launch_bounds__(256) k_strided_sums(const float* __restrict__ x,
                                                      float* __restrict__ Sout) {
    int t = threadIdx.x;
    int bc = blockIdx.x;
    const float4* xp = (const float4*)(x + (size_t)bc * (H_ * W_));
    float a[9];
#pragma unroll
    for (int k = 0; k < 9; k++) a[k] = 0.f;
#pragma unroll
    for (int k = 0; k < 16; k++) {
        int i4 = t + k * 256;
        int h = i4 >> 5;
        int w0 = (i4 & 31) << 2;
        float4 v = xp[i4];
        float mA = (w0 == 124) ? 0.f : 1.f;
        float mB = (w0 == 0) ? 0.f : 1.f;
        float rs0 = v.x + mA * v.z;
        float rs1 = v.y + mA * v.w;
        float rs2 = mB * v.x + v.z;
        float e  = (h & 1) ? 0.f : 1.f;
        float od = 1.f - e;
        float hm0 = (h == 126) ? 0.f : e;
        float hm2 = (h == 0)   ? 0.f : e;
        float hm1 = (h == 127) ? 0.f : od;
        a[0] = fmaf(hm0, rs0, a[0]); a[1] = fmaf(hm0, rs1, a[1]); a[2] = fmaf(hm0, rs2, a[2]);
        a[3] = fmaf(hm1, rs0, a[3]); a[4] = fmaf(hm1, rs1, a[4]); a[5] = fmaf(hm1, rs2, a[5]);
        a[6] = fmaf(hm2, rs0, a[6]); a[7] = fmaf(hm2, rs1, a[7]); a[8] = fmaf(hm2, rs2, a[8]);
    }
    __shared__ float red[4][9];
    int lane = t & 63, wv = t >> 6;
#pragma unroll
    for (int k = 0; k < 9; k++) {
        float v = a[k];
        for (int off = 32; off > 0; off >>= 1) v += __shfl_down(v, off);
        if (lane == 0) red[wv][k] = v;
    }
    __syncthreads();
    if (t < 9) Sout[(size_t)bc * 9 + t] = red[0][t] + red[1][t] + red[2][t] + red[3][t];
}

// K2: condition generator (unchanged)
__global__ void __launch_bounds__(256) k_cond(const float* __restrict__ S,
                       const float* __restrict__ w1, const float* __restrict__ b1,
                       const float* __restrict__ w2, const float* __restrict__ b2,
                       float* __restrict__ cond2) {
    int b = blockIdx.x;
    int t = threadIdx.x;
    int j = t >> 4, seg = t & 15;
    const float* Sb = S + b * 576;
    const float* w1j = w1 + j * 576;
    int i0 = seg * 36;
    float s = 0.f;
#pragma unroll 4
    for (int i = 0; i < 36; i++) s = fmaf(Sb[i0 + i], w1j[i0 + i], s);
    __shared__ float red[16][16];
    __shared__ float condv[16];
    red[j][seg] = s;
    __syncthreads();
    if (t < 16) {
        float acc = 0.f;
#pragma unroll
        for (int k = 0; k < 16; k++) acc += red[t][k];
        acc = acc * (1.f / 3969.f) + b1[t];
        condv[t] = fmaxf(acc, 0.f);
    }
    __syncthreads();
    if (t < 16) {
        float s2 = b2[t];
#pragma unroll
        for (int k = 0; k < 16; k++) s2 = fmaf(condv[k], w2[t * 16 + k], s2);
        cond2[b * 16 + t] = fmaxf(s2, 0.f);
    }
}

// K3: dynamic generators; pw emitted as bf16 [b][o][c] (unchanged)
__global__ void k_dyn(const float* __restrict__ cond2,
                      const float* __restrict__ wg_w, const float* __restrict__ wg_b,
                      const float* __restrict__ pg_w, const float* __restrict__ pg_b,
                      const float* __restrict__ bg_w, const float* __restrict__ bg_b,
                      float* __restrict__ dw, unsigned short* __restrict__ pwbf,
                      float* __restrict__ dbias) {
    int idx = blockIdx.x * 256 + threadIdx.x;
    if (idx < 18432) {                       // dw: [B][576]
        int b = idx / 576, r = idx - b * 576;
        const float* cd = cond2 + b * 16;
        float s = wg_b[r];
#pragma unroll
        for (int j = 0; j < 16; j++) s += cd[j] * wg_w[r * 16 + j];
        dw[idx] = fmaxf(s, 0.f);
    } else if (idx < 18432 + 131072) {       // pw: [B][O*C] -> bf16
        int k = idx - 18432;
        int b = k >> 12, r = k & 4095;
        const float* cd = cond2 + b * 16;
        float s = pg_b[r];
#pragma unroll
        for (int j = 0; j < 16; j++) s += cd[j] * pg_w[r * 16 + j];
        pwbf[k] = f2bf(fmaxf(s, 0.f));
    } else if (idx < 151552) {               // dbias: [B][64]
        int k = idx - 149504;
        int b = k >> 6, r = k & 63;
        const float* cd = cond2 + b * 16;
        float s = bg_b[r];
#pragma unroll
        for (int j = 0; j < 16; j++) s += cd[j] * bg_w[r * 16 + j];
        dbias[k] = s;
    }
}

// K4 v2: fused depthwise (fp32 stencil) + MFMA pointwise.
// Grid 2048 = (b, 2-row tile). Block 256 = 4 waves.
// Changes vs v1: conflict-free swizzled y (reg 4x4 transpose + b64 writes),
// K split into 2 halves of 32c (LDS 40,192 B -> 4 blocks/CU),
// global_load_lds double-buffered staging (1 barrier/iter),
// direct global stores from acc + in-register BN partials (no epi buffer).
struct SM4 {
    unsigned short y[256 * 36];   // [px][32c + 4 pad] = 72 B/row, XOR-swizzled  18432 B
    float xr[2][4][4][128];       // dbuf x 4 ch x 4 rows x 128                  16384 B
    float dwl[64 * 12];           // taps, padded to 12 for float4 reads          3072 B
    float sred[4][64];            //                                              1024 B
    float qred[4][64];            //                                              1024 B
    float dbl[64];                //                                               256 B
};                                // total 40,192 B  (<=40,960 -> 4 blocks/CU)

__global__ void __launch_bounds__(256, 4) k_fused(
        const float* __restrict__ x, const float* __restrict__ dw,
        const unsigned short* __restrict__ pwbf, const float* __restrict__ dbias,
        float* __restrict__ out, float* __restrict__ psum, float* __restrict__ psq) {
    __shared__ SM4 sm;
    int t = threadIdx.x;
    int bx = blockIdx.x;
    int b = bx >> 6;
    int pt = bx & 63;
    int h0 = pt << 1;

    int l = t & 63, w_id = t >> 6;
    int quad = l >> 4, l15 = l & 15;
    int pxbase = w_id << 6;

    // stencil mapping: m = c-offset within staged 4, px0 = 4-px group base
    int m = t & 3;
    int px0 = t & ~3;             // = 4*(t>>2)
    int h_loc = px0 >> 7;         // wave-uniform
    int w0 = px0 & 127;
    // boundary row masks (folded into taps)
    float mk0 = (h0 == 0   && h_loc == 0) ? 0.f : 1.f;   // row h0-1 invalid
    float mk2 = (h0 == 126 && h_loc == 1) ? 0.f : 1.f;   // row h0+2 invalid

    // stage taps (padded [c][12]) + dbias
    for (int i = t; i < 576; i += 256) {
        int c = i / 9, k = i - c * 9;
        sm.dwl[c * 12 + k] = dw[b * 576 + i];
    }
    if (t < 64) sm.dbl[t] = dbias[b * 64 + t];

    const float* xb = x + ((size_t)b << 20);
    const unsigned short* pwb = pwbf + (size_t)b * 4096;

    f32x4 acc[4][4];
#pragma unroll
    for (int i = 0; i < 4; i++)
#pragma unroll
        for (int j = 0; j < 4; j++) acc[i][j] = (f32x4){0.f, 0.f, 0.f, 0.f};

    // async stage of 4 channels x 4 rows into xr[bf] via global_load_lds (16B)
    auto stage = [&](int bf, int cbg) {
#pragma unroll
        for (int k2 = 0; k2 < 2; k2++) {
            int f4 = t + k2 * 256;
            int cc = f4 >> 7, rem = f4 & 127;
            int rr = rem >> 5, w4 = rem & 31;
            int hh = h0 - 1 + rr;
            hh = hh < 0 ? 0 : (hh > 127 ? 127 : hh);   // clamp; masked in taps
            const float* src = xb + ((size_t)(cbg + cc) << 14) + hh * 128 + (w4 << 2);
            float* dst = &sm.xr[bf][cc][rr][w4 << 2];
            __builtin_amdgcn_global_load_lds((gv_t*)src, (lv_t*)dst, 16, 0, 0);
        }
    };

    short8 bfr[4];
    auto load_bfr = [&](int hf) {
#pragma unroll
        for (int nt = 0; nt < 4; nt++) {
            int o = nt * 16 + l15;
            bfr[nt] = *(const short8*)(pwb + o * 64 + hf * 32 + quad * 8);
        }
    };

    auto domfma = [&]() {
        char* yb = (char*)sm.y;
#pragma unroll
        for (int mt = 0; mt < 4; mt++) {
            int px = pxbase + mt * 16 + l15;
            int bofs = px * 72;
            int sx = px & 7;
            short4v lo = *(short4v*)(yb + bofs + 8 * ((2 * quad)     ^ sx));
            short4v hi = *(short4v*)(yb + bofs + 8 * ((2 * quad + 1) ^ sx));
            short8 a = __builtin_shufflevector(lo, hi, 0, 1, 2, 3, 4, 5, 6, 7);
#pragma unroll
            for (int nt = 0; nt < 4; nt++)
                acc[mt][nt] = __builtin_amdgcn_mfma_f32_16x16x32_bf16(
                    a, bfr[nt], acc[mt][nt], 0, 0, 0);
        }
    };

    load_bfr(0);
    stage(0, 0);
    __syncthreads();     // taps + first tile ready

    int buf = 0;
#pragma unroll
    for (int idx = 0; idx < 16; idx++) {
        int cb = idx * 4;        // global channel base this iter
        int rp = idx & 7;        // c-slot within half (write swizzle slot)
        if (idx < 15) stage(buf ^ 1, cb + 4);   // prefetch next tile (async)

        // ---- stencil: 4 px (px0..px0+3) of channel cb+m, from xr[buf] ----
        const float* dvp = sm.dwl + (cb + m) * 12;
        float4 d0 = *(const float4*)(dvp);
        float4 d1 = *(const float4*)(dvp + 4);
        float4 d2 = *(const float4*)(dvp + 8);
        float dA0 = d0.x * mk0, dB0 = d0.y * mk0, dC0 = d0.z * mk0;
        float dA1 = d0.w,       dB1 = d1.x,       dC1 = d1.y;
        float dA2 = d1.z * mk2, dB2 = d1.w * mk2, dC2 = d2.x * mk2;
        const float* xc = &sm.xr[buf][m][0][0];
        float y0 = 0.f, y1 = 0.f, y2 = 0.f, y3 = 0.f;
#define STEN(dAx, dBx, dCx, KH) { \
        const float* row = xc + (h_loc + KH) * 128; \
        float4 fc = *(const float4*)(row + w0); \
        float4 fm = *(const float4*)(row + (w0 ? w0 - 4 : 0)); \
        float4 fp = *(const float4*)(row + ((w0 < 124) ? w0 + 4 : 120)); \
        float lft = w0 ? fm.w : 0.f; \
        float rgt = (w0 < 124) ? fp.x : 0.f; \
        y0 = fmaf(dAx, lft,  fmaf(dBx, fc.x, fmaf(dCx, fc.y, y0))); \
        y1 = fmaf(dAx, fc.x, fmaf(dBx, fc.y, fmaf(dCx, fc.z, y1))); \
        y2 = fmaf(dAx, fc.y, fmaf(dBx, fc.z, fmaf(dCx, fc.w, y2))); \
        y3 = fmaf(dAx, fc.z, fmaf(dBx, fc.w, fmaf(dCx, rgt, y3))); }
        STEN(dA0, dB0, dC0, 0)
        STEN(dA1, dB1, dC1, 1)
        STEN(dA2, dB2, dC2, 2)
#undef STEN

        // ---- 4x4 transpose within lane-quad: (1c,4px) -> (4c,1px) ----
        unsigned p01 = pk_bf16(y0, y1);
        unsigned p23 = pk_bf16(y2, y3);
        bool mhi = (m & 2) != 0;
        bool mlo = (m & 1) != 0;
        unsigned send0 = mhi ? p01 : p23;
        unsigned keep0 = mhi ? p23 : p01;
        unsigned x2 = (unsigned)__shfl_xor((int)send0, 2);
        unsigned Lw = mhi ? x2 : keep0;       // word for low c of {m, m^2}
        unsigned Hw = mhi ? keep0 : x2;       // word for high c
        unsigned E0 = (Lw & 0xFFFFu) | (Hw << 16);       // [L.lo, H.lo]
        unsigned E1 = (Lw >> 16) | (Hw & 0xFFFF0000u);   // [L.hi, H.hi]
        unsigned Zk = mlo ? E1 : E0;
        unsigned Zs = mlo ? E0 : E1;
        unsigned x1 = (unsigned)__shfl_xor((int)Zs, 1);
        unsigned Aw = mlo ? x1 : Zk;          // [c0, c2] @ my px
        unsigned Bw = mlo ? Zk : x1;          // [c1, c3] @ my px
        unsigned w01 = (Aw & 0xFFFFu) | (Bw << 16);
        unsigned w23 = (Aw >> 16) | (Bw & 0xFFFF0000u);
        int px = px0 | m;                     // == t
        int W = px * 72 + 8 * (rp ^ (px & 7));
        *(uint2*)((char*)sm.y + W) = make_uint2(w01, w23);

        __syncthreads();
        buf ^= 1;
        if (idx == 7) {       // half 0 complete: MFMA over c0..31
            domfma();
            __syncthreads();  // y reads done before half 1 overwrites
            load_bfr(1);
        }
    }
    domfma();                 // half 1: c32..63

    // ---- epilogue: direct stores + in-register BN partials ----
    float* outb = out + ((size_t)b << 20);
#pragma unroll
    for (int nt = 0; nt < 4; nt++) {
        int o = nt * 16 + l15;
        float dbv = sm.dbl[o];
        float s = 0.f, q = 0.f;
        float* og = outb + (size_t)o * 16384 + h0 * 128 + pxbase + quad * 4;
#pragma unroll
        for (int mt = 0; mt < 4; mt++) {
            f32x4 a = acc[mt][nt];
            float4 v = make_float4(a.x + dbv, a.y + dbv, a.z + dbv, a.w + dbv);
            s += v.x + v.y + v.z + v.w;
            q += v.x * v.x + v.y * v.y + v.z * v.z + v.w * v.w;
            *(float4*)(og + mt * 16) = v;
        }
        s += __shfl_xor(s, 16); s += __shfl_xor(s, 32);
        q += __shfl_xor(q, 16); q += __shfl_xor(q, 32);
        if (l < 16) { sm.sred[w_id][o] = s; sm.qred[w_id][o] = q; }
    }
    __syncthreads();
    if (t < 64) {
        float S = sm.sred[0][t] + sm.sred[1][t] + sm.sred[2][t] + sm.sred[3][t];
        float Q = sm.qred[0][t] + sm.qred[1][t] + sm.qred[2][t] + sm.qred[3][t];
        psum[(size_t)bx * 64 + t] = S;
        psq[(size_t)bx * 64 + t] = Q;
    }
}

// K5: reduce partials -> scale/shift (unchanged)
__global__ void k_bnstats(const float* __restrict__ psum, const float* __restrict__ psq,
                          const float* __restrict__ gamma, const float* __restrict__ beta,
                          float* __restrict__ scale, float* __restrict__ shift) {
    int o = blockIdx.x, t = threadIdx.x;
    float s = 0.f, q = 0.f;
    for (int i = t; i < 2048; i += 256) {
        s += psum[(size_t)i * 64 + o];
        q += psq[(size_t)i * 64 + o];
    }
    int lane = t & 63, wv = t >> 6;
    for (int off = 32; off > 0; off >>= 1) { s += __shfl_down(s, off); q += __shfl_down(q, off); }
    __shared__ float rs[4], rq[4];
    if (lane == 0) { rs[wv] = s; rq[wv] = q; }
    __syncthreads();
    if (t == 0) {
        float S = rs[0] + rs[1] + rs[2] + rs[3];
        float Q = rq[0] + rq[1] + rq[2] + rq[3];
        const float invN = 1.f / (float)(B_ * H_ * W_);
        float mean = S * invN;
        float var = fmaxf(Q * invN - mean * mean, 0.f);
        float sc = gamma[o] * rsqrtf(var + 1e-5f);
        scale[o] = sc;
        shift[o] = beta[o] - mean * sc;
    }
}

// K6: in-place BN apply (unchanged)
__global__ void __launch_bounds__(256) k_bnapply(float* __restrict__ out,
                          const float* __restrict__ scale, const float* __restrict__ shift) {
    __shared__ float ss[64], sh[64];
    int t = threadIdx.x;
    if (t < 64) { ss[t] = scale[t]; sh[t] = shift[t]; }
    __syncthreads();
    const int total4 = B_ * O_ * H_ * W_ / 4;
    float4* o4 = (float4*)out;
    for (int i = blockIdx.x * 256 + t; i < total4; i += gridDim.x * 256) {
        int o = (i >> 12) & 63;
        float sc = ss[o], sf = sh[o];
        float4 v = o4[i];
        v.x = fmaf(v.x, sc, sf);
        v.y = fmaf(v.y, sc, sf);
        v.z = fmaf(v.z, sc, sf);
        v.w = fmaf(v.w, sc, sf);
        o4[i] = v;
    }
}

extern "C" void kernel_launch(void* const* d_in, const int* in_sizes, int n_in,
                              void* d_out, int out_size, void* d_ws, size_t ws_size,
                              hipStream_t stream) {
    const float* x     = (const float*)d_in[0];
    const float* cg_w1 = (const float*)d_in[1];
    const float* cg_b1 = (const float*)d_in[2];
    const float* cg_w2 = (const float*)d_in[3];
    const float* cg_b2 = (const float*)d_in[4];
    const float* wg_w  = (const float*)d_in[5];
    const float* wg_b  = (const float*)d_in[6];
    const float* pg_w  = (const float*)d_in[7];
    const float* pg_b  = (const float*)d_in[8];
    const float* bg_w  = (const float*)d_in[9];
    const float* bg_b  = (const float*)d_in[10];
    const float* bn_g  = (const float*)d_in[11];
    const float* bn_b  = (const float*)d_in[12];
    float* out = (float*)d_out;
    float* ws  = (float*)d_ws;

    float* S     = ws + WS_S;
    float* cond2 = ws + WS_COND2;
    float* dw    = ws + WS_DW;
    float* dbias = ws + WS_DBIAS;
    unsigned short* pwbf = (unsigned short*)(ws + WS_PWBF);
    float* psum  = ws + WS_PSUM;
    float* psq   = ws + WS_PSQ;
    float* scale = ws + WS_SCALE;
    float* shift = ws + WS_SHIFT;

    k_strided_sums<<<B_ * C_, 256, 0, stream>>>(x, S);
    k_cond<<<B_, 256, 0, stream>>>(S, cg_w1, cg_b1, cg_w2, cg_b2, cond2);
    k_dyn<<<(151552 + 255) / 256, 256, 0, stream>>>(cond2, wg_w, wg_b, pg_w, pg_b,
                                                    bg_w, bg_b, dw, pwbf, dbias);
    k_fused<<<2048, 256, 0, stream>>>(x, dw, pwbf, dbias, out, psum, psq);
    k_bnstats<<<O_, 256, 0, stream>>>(psum, psq, bn_g, bn_b, scale, shift);
    k_bnapply<<<4096, 256, 0, stream>>>(out, scale, shift);
}